// Round 8
// baseline (503.984 us; speedup 1.0000x reference)
//
#include <hip/hip_runtime.h>
#include <hip/hip_bf16.h>

typedef __hip_bfloat16 bf16;
typedef __attribute__((ext_vector_type(8))) short bf16x8;
typedef __attribute__((ext_vector_type(4))) short s16x4;
typedef __attribute__((ext_vector_type(4))) float f32x4;
typedef __attribute__((ext_vector_type(2))) unsigned int u32x2;

__device__ __forceinline__ float b2f(bf16 v) { return __bfloat162float(v); }
__device__ __forceinline__ bf16  f2b(float v) { return __float2bfloat16(v); }
__device__ __forceinline__ float ldf(const bf16* p)  { return __bfloat162float(*p); }
__device__ __forceinline__ float ldf(const float* p) { return *p; }
__device__ __forceinline__ void  stf(bf16* p, float v)  { *p = __float2bfloat16(v); }
__device__ __forceinline__ void  stf(float* p, float v) { *p = v; }

// HW packed f32x2 -> bf16x2 convert (RNE). No builtin on gfx950 (T12 recipe).
__device__ __forceinline__ unsigned cvt_pk_bf16(float lo, float hi) {
    unsigned r;
    asm("v_cvt_pk_bf16_f32 %0, %1, %2" : "=v"(r) : "v"(lo), "v"(hi));
    return r;
}

// vectorized 4-element row loads for LayerNorm
__device__ __forceinline__ void ld4(const float* p, float* v) {
    float4 t = *(const float4*)p;
    v[0] = t.x; v[1] = t.y; v[2] = t.z; v[3] = t.w;
}
__device__ __forceinline__ void ld4(const bf16* p, float* v) {
    s16x4 t = *(const s16x4*)p;
#pragma unroll
    for (int j = 0; j < 4; ++j) { short s = t[j]; v[j] = b2f(*(bf16*)&s); }
}

// async global->LDS, 16 B per lane; LDS dest = wave-uniform base + lane*16
__device__ __forceinline__ void load_lds16(const bf16* g, short* lds) {
    __builtin_amdgcn_global_load_lds(
        (const __attribute__((address_space(1))) unsigned int*)g,
        (__attribute__((address_space(3))) unsigned int*)lds, 16, 0, 0);
}

// ---------------------------------------------------------------------------
// LayerNorm over last dim C=1024. One block (256 threads) per row. bf16 out.
// ---------------------------------------------------------------------------
template<typename InT>
__global__ __launch_bounds__(256) void ln_kernel(const InT* __restrict__ x,
                                                 const float* __restrict__ g,
                                                 const float* __restrict__ b,
                                                 bf16* __restrict__ out)
{
    const int C = 1024;
    int row = blockIdx.x;
    int tid = threadIdx.x;
    const InT* xr = x + (size_t)row * C;

    float v[4];
    ld4(xr + tid * 4, v);
    float s = 0.f, s2 = 0.f;
#pragma unroll
    for (int i = 0; i < 4; ++i) { s += v[i]; s2 += v[i] * v[i]; }
#pragma unroll
    for (int off = 32; off > 0; off >>= 1) {
        s  += __shfl_down(s,  off, 64);
        s2 += __shfl_down(s2, off, 64);
    }
    __shared__ float red[8];
    int wave = tid >> 6;
    if ((tid & 63) == 0) { red[wave] = s; red[wave + 4] = s2; }
    __syncthreads();
    float ts  = red[0] + red[1] + red[2] + red[3];
    float ts2 = red[4] + red[5] + red[6] + red[7];
    float mu  = ts * (1.f / 1024.f);
    float var = ts2 * (1.f / 1024.f) - mu * mu;
    float rstd = rsqrtf(var + 1e-5f);

    float4 gg = *(const float4*)(g + tid * 4);
    float4 bb = *(const float4*)(b + tid * 4);
    float gj[4] = {gg.x, gg.y, gg.z, gg.w};
    float bj[4] = {bb.x, bb.y, bb.z, bb.w};
    s16x4 o4;
#pragma unroll
    for (int j = 0; j < 4; ++j) {
        bf16 ob = f2b((v[j] - mu) * rstd * gj[j] + bj[j]);
        o4[j] = *(short*)&ob;
    }
    *(s16x4*)(out + (size_t)row * C + tid * 4) = o4;
}

// ---------------------------------------------------------------------------
// All six weight transposes (fp32 -> bf16, out[n][k] = in[k][n]) in ONE
// kernel. Flat tile id selects matrix + 32x32 tile.
// ---------------------------------------------------------------------------
__global__ __launch_bounds__(256) void prep_weights(
    const float* __restrict__ Wq, const float* __restrict__ Wk,
    const float* __restrict__ Wv, const float* __restrict__ Wo,
    const float* __restrict__ W1, const float* __restrict__ W2,
    bf16* __restrict__ wqkvt, bf16* __restrict__ wot,
    bf16* __restrict__ w1t, bf16* __restrict__ w2t)
{
    __shared__ float t[32][33];
    int tx = threadIdx.x & 31, ty = threadIdx.x >> 5;
    int id = blockIdx.x;
    const float* in; bf16* out; int in_ld, out_ld, n0, k0;
    if (id < 3072) {
        const float* Ws[3] = {Wq, Wk, Wv};
        int m = id >> 10, r = id & 1023;
        int z = r >> 6, rt = r & 63;
        in = Ws[m] + z * 65536;                       // [1024][64]
        out = wqkvt + (size_t)(m * 1024 + z * 64) * 1024;
        in_ld = 64; out_ld = 1024;
        n0 = (rt & 1) * 32; k0 = (rt >> 1) * 32;
    } else if (id < 4096) {
        int r = id - 3072;
        in = Wo; out = wot; in_ld = 1024; out_ld = 1024;
        n0 = (r & 31) * 32; k0 = (r >> 5) * 32;
    } else if (id < 8192) {
        int r = id - 4096;
        in = W1; out = w1t; in_ld = 4096; out_ld = 1024;
        n0 = (r & 127) * 32; k0 = (r >> 7) * 32;
    } else {
        int r = id - 8192;
        in = W2; out = w2t; in_ld = 1024; out_ld = 4096;
        n0 = (r & 31) * 32; k0 = (r >> 5) * 32;
    }
#pragma unroll
    for (int i = 0; i < 4; ++i)
        t[ty + i * 8][tx] = in[(size_t)(k0 + ty + i * 8) * in_ld + n0 + tx];
    __syncthreads();
#pragma unroll
    for (int i = 0; i < 4; ++i)
        out[(size_t)(n0 + ty + i * 8) * out_ld + k0 + tx] = f2b(t[tx][ty + i * 8]);
}

// ---------------------------------------------------------------------------
// V^T: vt[(b*16+h)*64 + d][t] = qkv[(b*T+t)*3072 + 2048 + h*64 + d]
// ---------------------------------------------------------------------------
__global__ __launch_bounds__(256) void vt_kernel(
    const bf16* __restrict__ qkv, bf16* __restrict__ vt, int T)
{
    __shared__ float t[32][33];
    int tx = threadIdx.x & 31, ty = threadIdx.x >> 5;
    int z = blockIdx.z, b = z >> 4, h = z & 15;
    const bf16* in = qkv + (size_t)b * T * 3072 + 2048 + h * 64;  // [t][d] ld 3072
    bf16* out = vt + (size_t)z * 64 * T;                          // [d][t] ld T
    int n0 = blockIdx.x * 32, k0 = blockIdx.y * 32;
#pragma unroll
    for (int i = 0; i < 4; ++i)
        t[ty + i * 8][tx] = b2f(in[(size_t)(k0 + ty + i * 8) * 3072 + n0 + tx]);
    __syncthreads();
#pragma unroll
    for (int i = 0; i < 4; ++i)
        out[(size_t)(n0 + ty + i * 8) * T + k0 + tx] = f2b(t[tx][ty + i * 8]);
}

// ---------------------------------------------------------------------------
// 256x256 MFMA GEMM (T2+T3+T4+T5), plain HIP. 512 thr = 8 waves.
// BK=32, FOUR LDS buffers (128 KB), staging 3 tiles ahead alias-free.
// PIPELINED FRAGMENT READS: each phase issues the ds_reads for the NEXT
// phase's fragments before its own MFMA cluster, so the lgkmcnt before the
// MFMAs waits only on last-phase reads (already returned) and the new reads'
// LDS latency hides under the 16-MFMA cluster. B-fragments are live across
// both quadrant phases -> 2-set register rotation (bfA/bfB) via a
// 2x-unrolled k-loop (static indexing). A-fragments die after their quadrant
// and are overwritten in place.
//   ph0(t): stage A(t+3) | bar | read ag=af4-7(t) | 16 MFMA (af x BU) | bar
//   ph1(t): stage B(t+3) | counted vmcnt | bar | read af(t+1),BV(t+1) |
//           16 MFMA (ag x BU) | bar
// Counted vmcnt (NEVER 0 in steady state): vmcnt(8) at ph1 => tile t+1
// resident for the reads right after the barrier. Tail: 8 -> 4 -> 0.
// Swizzle: verified 0-conflict scheme.
// Requires: M%256==0, N%256==0, K%32==0, K/32>=4 and EVEN, grid %8==0.
// ---------------------------------------------------------------------------
template<bool RELU, bool HAS_BIAS, typename OutT>
__global__ __launch_bounds__(512, 2) void gemm8p(
    const bf16* __restrict__ A, int lda,
    const bf16* __restrict__ Bt, int ldb,
    const float* __restrict__ bias,
    OutT* __restrict__ Cm, int ldc,
    int M, int N, int K)
{
    __shared__ short As[4][8192];
    __shared__ short Bs[4][8192];
    int tid = threadIdx.x, wv = tid >> 6, ln = tid & 63;
    int quad = ln >> 4, lane15 = ln & 15;

    // XCD-chunked bijective remap (nwg % 8 == 0)
    int nbn = N >> 8;
    int nwg = gridDim.x;
    int f2 = (blockIdx.x & 7) * (nwg >> 3) + (blockIdx.x >> 3);
    int by = f2 / nbn, bx = f2 % nbn;
    int bm0 = by << 8, bn0 = bx << 8;

    int wr = wv >> 2, wc = wv & 3;     // wave row-half / col-quarter
    const int NT = K >> 5;

    // staging addresses (per thread); linear LDS dest, swizzled source
    int sr = tid >> 2;                                  // row 0..127
    int sc = ((tid & 3) ^ ((sr >> 1) & 3)) * 8;
    const bf16* Ab1 = A  + (size_t)(bm0 + sr) * lda + sc;
    const bf16* Ab2 = A  + (size_t)(bm0 + 128 + sr) * lda + sc;
    const bf16* Bb1 = Bt + (size_t)(bn0 + sr) * ldb + sc;
    const bf16* Bb2 = Bt + (size_t)(bn0 + 128 + sr) * ldb + sc;

#define STAGE_A8(bf_, u_) { \
    load_lds16(Ab1 + (u_) * 32, &As[bf_][wv * 512]); \
    load_lds16(Ab2 + (u_) * 32, &As[bf_][4096 + wv * 512]); }
#define STAGE_B8(bf_, u_) { \
    load_lds16(Bb1 + (u_) * 32, &Bs[bf_][wv * 512]); \
    load_lds16(Bb2 + (u_) * 32, &Bs[bf_][4096 + wv * 512]); }

    f32x4 acc[8][4] = {};                 // 128 VGPRs
    int arow = wr * 128 + lane15;
    int brow = wc * 64 + lane15;
    int sw = (quad ^ ((lane15 >> 1) & 3)) * 8;

    // prologue: stage tiles 0,1,2; wait tile 0 (8 loads stay in flight)
    STAGE_A8(0, 0); STAGE_B8(0, 0);
    STAGE_A8(1, 1); STAGE_B8(1, 1);
    STAGE_A8(2, 2); STAGE_B8(2, 2);
    asm volatile("s_waitcnt vmcnt(8)" ::: "memory");
    __builtin_amdgcn_s_barrier();

    bf16x8 af[4], ag[4], bfA[4], bfB[4];
    // pre-read tile 0's phase-0 fragments (tile 0 resident block-wide:
    // every wave executed vmcnt(8) before the barrier above)
#pragma unroll
    for (int mi = 0; mi < 4; ++mi)
        af[mi] = *(const bf16x8*)&As[0][(arow + mi * 16) * 32 + sw];
#pragma unroll
    for (int ni = 0; ni < 4; ++ni)
        bfA[ni] = *(const bf16x8*)&Bs[0][(brow + ni * 16) * 32 + sw];

    auto iter = [&](int t, bf16x8 (&BU)[4], bf16x8 (&BV)[4]) {
        int buf = t & 3;
        const short* Al = &As[buf][0];

        // ---- phase 0: stage A(t+3); MFMA Q0 (af x BU, read last phase);
        //      issue ag = af4-7(t) reads under the MFMA cluster
        if (t + 3 < NT) STAGE_A8((t + 3) & 3, t + 3);
        __builtin_amdgcn_s_barrier();
#pragma unroll
        for (int mi = 0; mi < 4; ++mi)
            ag[mi] = *(const bf16x8*)&Al[(arow + (mi + 4) * 16) * 32 + sw];
        __builtin_amdgcn_s_setprio(1);
#pragma unroll
        for (int mi = 0; mi < 4; ++mi)
#pragma unroll
            for (int ni = 0; ni < 4; ++ni)
                acc[mi][ni] = __builtin_amdgcn_mfma_f32_16x16x32_bf16(
                    af[mi], BU[ni], acc[mi][ni], 0, 0, 0);
        __builtin_amdgcn_s_setprio(0);
        __builtin_amdgcn_s_barrier();

        // ---- phase 1: stage B(t+3); counted vmcnt; MFMA Q1 (ag x BU);
        //      issue af(t+1), BV(t+1) reads under the MFMA cluster
        if (t + 3 < NT) STAGE_B8((t + 3) & 3, t + 3);
        if (t < NT - 3) {
            asm volatile("s_waitcnt vmcnt(8)" ::: "memory");   // tile t+1 landed
        } else if (t == NT - 3) {
            asm volatile("s_waitcnt vmcnt(4)" ::: "memory");
        } else if (t == NT - 2) {
            asm volatile("s_waitcnt vmcnt(0)" ::: "memory");   // tail only
        }
        __builtin_amdgcn_s_barrier();
        if (t + 1 < NT) {
            const short* Aln = &As[(t + 1) & 3][0];
            const short* Bln = &Bs[(t + 1) & 3][0];
#pragma unroll
            for (int mi = 0; mi < 4; ++mi)
                af[mi] = *(const bf16x8*)&Aln[(arow + mi * 16) * 32 + sw];
#pragma unroll
            for (int ni = 0; ni < 4; ++ni)
                BV[ni] = *(const bf16x8*)&Bln[(brow + ni * 16) * 32 + sw];
        }
        __builtin_amdgcn_s_setprio(1);
#pragma unroll
        for (int mi = 0; mi < 4; ++mi)
#pragma unroll
            for (int ni = 0; ni < 4; ++ni)
                acc[mi + 4][ni] = __builtin_amdgcn_mfma_f32_16x16x32_bf16(
                    ag[mi], BU[ni], acc[mi + 4][ni], 0, 0, 0);
        __builtin_amdgcn_s_setprio(0);
        __builtin_amdgcn_s_barrier();
    };

    for (int tt = 0; tt < NT; tt += 2) {
        iter(tt,     bfA, bfB);
        iter(tt + 1, bfB, bfA);
    }

#undef STAGE_A8
#undef STAGE_B8

    // ---- epilogue
#pragma unroll
    for (int mi = 0; mi < 8; ++mi) {
#pragma unroll
        for (int r = 0; r < 4; ++r) {
            int gm = bm0 + wr * 128 + mi * 16 + quad * 4 + r;
#pragma unroll
            for (int ni = 0; ni < 4; ++ni) {
                int gn = bn0 + wc * 64 + ni * 16 + lane15;
                float v = acc[mi][ni][r];
                if (HAS_BIAS) v += bias[gn];
                if (RELU)     v = fmaxf(v, 0.f);
                stf(Cm + (size_t)gm * ldc + gn, v);
            }
        }
    }
}

// ---------------------------------------------------------------------------
// MFMA GEMM: C[M,N] = A[M,K] @ B[K,N], B given TRANSPOSED (Bt[n][k]).
// 128x128 tile, 256 thr = 4 waves, templated BK (32 or 64). Double-buffered
// LDS, stage-before-compute, one __syncthreads per K-step. Used for the
// N=1024 GEMMs (Wo, FFN2) where 256-wide col tiles would underfill the grid.
// ---------------------------------------------------------------------------
template<int BK, bool RELU, bool HAS_BIAS, bool HAS_RES, typename ResT, typename OutT>
__global__ __launch_bounds__(256) void gemm_bt(
    const bf16* __restrict__ A, int lda,
    const bf16* __restrict__ Bt, int ldb,
    const float* __restrict__ bias,
    const ResT* __restrict__ res, int ldr,
    OutT* __restrict__ Cm, int ldc,
    int M, int N, int K)
{
    __shared__ short As[2][128 * BK];
    __shared__ short Bs[2][128 * BK];
    int tid = threadIdx.x, wv = tid >> 6, ln = tid & 63;

    int f = blockIdx.x + blockIdx.y * gridDim.x;
    int nby = gridDim.y;
    int by = f % nby, bx = f / nby;
    int bm0 = by * 128, bn0 = bx * 128;

    int wm = (wv & 1) * 64, wn = (wv >> 1) * 64;
    int quad = ln >> 4, lane15 = ln & 15;

    f32x4 acc[4][4] = {};

    const bf16* Ab = A + (size_t)bm0 * lda;
    const bf16* Bb = Bt + (size_t)bn0 * ldb;

    auto stage = [&](int buf, int kk) {
        if constexpr (BK == 32) {
            int srow = ln >> 2;
            int scol = (((ln & 3) ^ ((ln >> 3) & 3)) * 8);
#pragma unroll
            for (int i = 0; i < 2; ++i) {
                int ch = wv + i * 4;
                load_lds16(Ab + (size_t)(ch * 16 + srow) * lda + kk + scol,
                           &As[buf][ch * 16 * 32]);
                load_lds16(Bb + (size_t)(ch * 16 + srow) * ldb + kk + scol,
                           &Bs[buf][ch * 16 * 32]);
            }
        } else {
            int srow = ln >> 3;
            int scol = ((ln & 7) ^ srow) * 8;
#pragma unroll
            for (int i = 0; i < 4; ++i) {
                int r0 = i * 32 + wv * 8;
                load_lds16(Ab + (size_t)(r0 + srow) * lda + kk + scol,
                           &As[buf][r0 * 64]);
                load_lds16(Bb + (size_t)(r0 + srow) * ldb + kk + scol,
                           &Bs[buf][r0 * 64]);
            }
        }
    };

    stage(0, 0);
    __syncthreads();

    int cur = 0;
    for (int k0 = 0; k0 < K; k0 += BK) {
        if (k0 + BK < K) stage(cur ^ 1, k0 + BK);
        if constexpr (BK == 32) {
            int sw = (quad ^ ((lane15 >> 1) & 3)) * 8;
            bf16x8 af[4], bfr[4];
#pragma unroll
            for (int mi = 0; mi < 4; ++mi)
                af[mi] = *(const bf16x8*)&As[cur][(wm + mi * 16 + lane15) * 32 + sw];
#pragma unroll
            for (int ni = 0; ni < 4; ++ni)
                bfr[ni] = *(const bf16x8*)&Bs[cur][(wn + ni * 16 + lane15) * 32 + sw];
#pragma unroll
            for (int mi = 0; mi < 4; ++mi)
#pragma unroll
                for (int ni = 0; ni < 4; ++ni)
                    acc[mi][ni] = __builtin_amdgcn_mfma_f32_16x16x32_bf16(
                        af[mi], bfr[ni], acc[mi][ni], 0, 0, 0);
        } else {
#pragma unroll
            for (int ks = 0; ks < 2; ++ks) {
                int sw = (((ks * 4 + quad) ^ (lane15 & 7)) * 8);
                bf16x8 af[4], bfr[4];
#pragma unroll
                for (int mi = 0; mi < 4; ++mi)
                    af[mi] = *(const bf16x8*)&As[cur][(wm + mi * 16 + lane15) * 64 + sw];
#pragma unroll
                for (int ni = 0; ni < 4; ++ni)
                    bfr[ni] = *(const bf16x8*)&Bs[cur][(wn + ni * 16 + lane15) * 64 + sw];
#pragma unroll
                for (int mi = 0; mi < 4; ++mi)
#pragma unroll
                    for (int ni = 0; ni < 4; ++ni)
                        acc[mi][ni] = __builtin_amdgcn_mfma_f32_16x16x32_bf16(
                            af[mi], bfr[ni], acc[mi][ni], 0, 0, 0);
            }
        }
        __syncthreads();
        cur ^= 1;
    }

#pragma unroll
    for (int mi = 0; mi < 4; ++mi) {
#pragma unroll
        for (int r = 0; r < 4; ++r) {
            int gm = bm0 + wm + mi * 16 + quad * 4 + r;
#pragma unroll
            for (int ni = 0; ni < 4; ++ni) {
                int gn = bn0 + wn + ni * 16 + lane15;
                float v = acc[mi][ni][r];
                if (HAS_BIAS) v += bias[gn];
                if (HAS_RES)  v += ldf(res + (size_t)gm * ldr + gn);
                if (RELU)     v = fmaxf(v, 0.f);
                stf(Cm + (size_t)gm * ldc + gn, v);
            }
        }
    }
}

// ---------------------------------------------------------------------------
// One q-tile's work for one 64-key tile: QK^T (S^T form), CONSTANT-SHIFT
// softmax in exp2 domain (no online max: softmax is shift-invariant and for
// LN'd inputs max|S*scale2| ~ 10 << f32 exp2 range; masked lanes give
// exp2(-huge) = 0 exactly), P->LDS (wave-private, cvt_pk packed), PV.
// ---------------------------------------------------------------------------
__device__ __forceinline__ void attn_tile_q(
    const short* __restrict__ Ks, const short* __restrict__ Vs,
    short* __restrict__ Psw,
    const bf16x8* qf, f32x4* oacc, float& lrun,
    int ktbase, int qmin, int quad, int lane15, int r7)
{
    const float scale2 = 0.18033688011112042f;   // (1/8) * log2(e)
    const int PS = 72;
    f32x4 sacc[4] = {};
    __builtin_amdgcn_s_setprio(1);
#pragma unroll
    for (int ks = 0; ks < 2; ++ks) {
        int so = ((ks * 4 + quad) ^ r7) * 8;
#pragma unroll
        for (int mi = 0; mi < 4; ++mi) {
            bf16x8 kf = *(const bf16x8*)&Ks[(mi * 16 + lane15) * 64 + so];
            sacc[mi] = __builtin_amdgcn_mfma_f32_16x16x32_bf16(kf, qf[ks], sacc[mi], 0, 0, 0);
        }
    }
    __builtin_amdgcn_s_setprio(0);

    if (ktbase + 63 > qmin) {
        int ql = qmin + lane15;
#pragma unroll
        for (int mi = 0; mi < 4; ++mi)
#pragma unroll
            for (int r = 0; r < 4; ++r)
                if (ktbase + mi * 16 + quad * 4 + r > ql) sacc[mi][r] = -3e38f;
    }

    float psum = 0.f;
#pragma unroll
    for (int mi = 0; mi < 4; ++mi) {
        float p[4];
#pragma unroll
        for (int r = 0; r < 4; ++r) {
            p[r] = exp2f(sacc[mi][r] * scale2);
            psum += p[r];
        }
        u32x2 pu;
        pu[0] = cvt_pk_bf16(p[0], p[1]);
        pu[1] = cvt_pk_bf16(p[2], p[3]);
        *(u32x2*)&Psw[lane15 * PS + mi * 16 + quad * 4] = pu;
    }
    lrun += psum;

    __builtin_amdgcn_s_setprio(1);
#pragma unroll
    for (int ks = 0; ks < 2; ++ks) {
        int so = ((ks * 4 + quad) ^ r7) * 8;
        bf16x8 pf = *(const bf16x8*)&Psw[lane15 * PS + ks * 32 + quad * 8];
#pragma unroll
        for (int di = 0; di < 4; ++di) {
            bf16x8 vf = *(const bf16x8*)&Vs[(di * 16 + lane15) * 64 + so];
            oacc[di] = __builtin_amdgcn_mfma_f32_16x16x32_bf16(vf, pf, oacc[di], 0, 0, 0);
        }
    }
    __builtin_amdgcn_s_setprio(0);
}

// ---------------------------------------------------------------------------
// MFMA causal flash attention, S^T form, 512 thr = 8 waves.
// CAUSAL-BALANCED DUAL Q-TILE: block bx processes q-tiles (15-bx, bx) in ONE
// k-loop sharing K/V staging. Every block does exactly 34 tile-units.
// Constant-shift softmax: no running max, no rescale (see attn_tile_q).
// ---------------------------------------------------------------------------
__global__ __launch_bounds__(512, 4) void attn_kernel(
    const bf16* __restrict__ qkv, const bf16* __restrict__ vt,
    bf16* __restrict__ o, int T)
{
    const int LDQ = 3072;
    const int PS = 72;
    int bx = blockIdx.x;
    int qta = 15 - bx;
    int qtb = bx;
    int h = blockIdx.y, b = blockIdx.z;
    int tid = threadIdx.x, wv = tid >> 6, ln = tid & 63;
    int quad = ln >> 4, lane15 = ln & 15, r7 = lane15 & 7;

    __shared__ short KV[2][2][64 * 64];
    __shared__ short Ps[2][8][16 * PS];

    int lr = ln >> 3;
    int lc = ((ln & 7) ^ lr) * 8;

    const bf16* kbase = qkv + (size_t)(b * T) * LDQ + 1024 + h * 64;
    const bf16* vbase = vt + (size_t)((b * 16 + h) * 64) * T;

#pragma unroll
    for (int i = 0; i < 2; ++i) {
        int ch = wv * 2 + i;
        load_lds16(qkv + (size_t)(b * T + qta * 128 + ch * 8 + lr) * LDQ + h * 64 + lc,
                   &KV[0][0][ch * 512]);
        load_lds16(qkv + (size_t)(b * T + qtb * 128 + ch * 8 + lr) * LDQ + h * 64 + lc,
                   &KV[1][0][ch * 512]);
    }
    __syncthreads();
    bf16x8 qfa[2], qfb[2];
#pragma unroll
    for (int ks = 0; ks < 2; ++ks) {
        int off = (wv * 16 + lane15) * 64 + (((ks * 4 + quad) ^ r7) * 8);
        qfa[ks] = *(const bf16x8*)&KV[0][0][off];
        qfb[ks] = *(const bf16x8*)&KV[1][0][off];
    }
    __syncthreads();

    f32x4 oacca[4] = {}, oaccb[4] = {};
    float lra = 0.f, lrb = 0.f;
    int qmina = qta * 128 + wv * 16;
    int qminb = qtb * 128 + wv * 16;
    int ntiles = 2 * qta + 2;

    // per-thread incremental staging pointers (tile 0)
    const bf16* kp = kbase + (size_t)(wv * 8 + lr) * LDQ + lc;
    const bf16* vp = vbase + (size_t)(wv * 8 + lr) * T + lc;
    load_lds16(kp, &KV[0][0][wv * 8 * 64]);
    load_lds16(vp, &KV[0][1][wv * 8 * 64]);

    for (int kt = 0; kt < ntiles; ++kt) {
        __syncthreads();
        if (kt + 1 < ntiles) {
            int nb = (kt + 1) & 1;
            kp += 64 * LDQ;     // next key tile: +64 rows
            vp += 64;           // next key tile: +64 cols
            load_lds16(kp, &KV[nb][0][wv * 8 * 64]);
            load_lds16(vp, &KV[nb][1][wv * 8 * 64]);
        }
        const short* Ks = &KV[kt & 1][0][0];
        const short* Vs = &KV[kt & 1][1][0];
        int kb = kt * 64;

        if (kb <= qmina + 15)
            attn_tile_q(Ks, Vs, &Ps[0][wv][0], qfa, oacca, lra,
                        kb, qmina, quad, lane15, r7);
        if (kb <= qminb + 15)
            attn_tile_q(Ks, Vs, &Ps[1][wv][0], qfb, oaccb, lrb,
                        kb, qminb, quad, lane15, r7);
    }

    lra += __shfl_xor(lra, 16, 64);
    lra += __shfl_xor(lra, 32, 64);
    float inva = 1.f / lra;
    size_t rowa = (size_t)(b * T + qta * 128 + wv * 16 + lane15);
#pragma unroll
    for (int di = 0; di < 4; ++di) {
        u32x2 ou;
        ou[0] = cvt_pk_bf16(oacca[di][0] * inva, oacca[di][1] * inva);
        ou[1] = cvt_pk_bf16(oacca[di][2] * inva, oacca[di][3] * inva);
        *(u32x2*)&o[rowa * 1024 + h * 64 + di * 16 + quad * 4] = ou;
    }

    lrb += __shfl_xor(lrb, 16, 64);
    lrb += __shfl_xor(lrb, 32, 64);
    float invb = 1.f / lrb;
    size_t rowb = (size_t)(b * T + qtb * 128 + wv * 16 + lane15);
#pragma unroll
    for (int di = 0; di < 4; ++di) {
        u32x2 ou;
        ou[0] = cvt_pk_bf16(oaccb[di][0] * invb, oaccb[di][1] * invb);
        ou[1] = cvt_pk_bf16(oaccb[di][2] * invb, oaccb[di][3] * invb);
        *(u32x2*)&o[rowb * 1024 + h * 64 + di * 16 + quad * 4] = ou;
    }
}

// ---------------------------------------------------------------------------
extern "C" void kernel_launch(void* const* d_in, const int* in_sizes, int n_in,
                              void* d_out, int out_size, void* d_ws, size_t ws_size,
                              hipStream_t stream)
{
    (void)in_sizes; (void)n_in; (void)out_size; (void)ws_size;
    const float* x   = (const float*)d_in[0];
    const float* Wq  = (const float*)d_in[1];
    const float* Wk  = (const float*)d_in[2];
    const float* Wv  = (const float*)d_in[3];
    const float* Wo  = (const float*)d_in[4];
    const float* bo  = (const float*)d_in[5];
    const float* g1  = (const float*)d_in[6];
    const float* be1 = (const float*)d_in[7];
    const float* g2  = (const float*)d_in[8];
    const float* be2 = (const float*)d_in[9];
    const float* W1  = (const float*)d_in[10];
    const float* b1  = (const float*)d_in[11];
    const float* W2  = (const float*)d_in[12];
    const float* b2  = (const float*)d_in[13];

    const int T = 2048, M = 4 * T;  // 8192 rows
    const size_t MB = 1ull << 20;
    char* ws = (char*)d_ws;

    // workspace map (128 MB, live-range overlays):
    bf16*  xn    = (bf16*)(ws + 0 * MB);     // 16 MB; later: attnb; later: hb
    bf16*  qkv   = (bf16*)(ws + 16 * MB);    // 48 MB [M][3072]; later: hb tail
    bf16*  vt    = (bf16*)(ws + 64 * MB);    // 16 MB [b*16+h][64][T]
    bf16*  wqkvt = (bf16*)(ws + 80 * MB);    //  6 MB [3072][1024]; later: x1b
    bf16*  x1b   = (bf16*)(ws + 80 * MB);    // 16 MB [M][1024] bf16 residual
    bf16*  wot   = (bf16*)(ws + 96 * MB);    //  2 MB; later: xn2
    bf16*  xn2   = (bf16*)(ws + 96 * MB);    // 16 MB
    bf16*  w1t   = (bf16*)(ws + 112 * MB);   //  8 MB [4096][1024]
    bf16*  w2t   = (bf16*)(ws + 120 * MB);   //  8 MB [1024][4096]
    bf16*  attnb = (bf16*)(ws + 0 * MB);
    bf16*  hb    = (bf16*)(ws + 0 * MB);     // 64 MB [M][4096]

    dim3 blk(256);

    prep_weights<<<12288, blk, 0, stream>>>(Wq, Wk, Wv, Wo, W1, W2,
                                            wqkvt, wot, w1t, w2t);

    ln_kernel<float><<<M, blk, 0, stream>>>(x, g1, be1, xn);

    // QKV: 256^2 pipelined 8-phase, grid 32x12 = 384
    gemm8p<false, false, bf16><<<dim3(384), dim3(512), 0, stream>>>(
        xn, 1024, wqkvt, 1024, nullptr, qkv, 3072, M, 3072, 1024);

    vt_kernel<<<dim3(2, T / 32, 64), blk, 0, stream>>>(qkv, vt, T);

    attn_kernel<<<dim3(8, 16, 4), dim3(512), 0, stream>>>(qkv, vt, attnb, T);

    gemm_bt<32, false, true, true, float, bf16><<<dim3(8, 64), blk, 0, stream>>>(
        attnb, 1024, wot, 1024, bo, x, 1024, x1b, 1024, M, 1024, 1024);

    ln_kernel<bf16><<<M, blk, 0, stream>>>(x1b, g2, be2, xn2);

    // FFN1: 256^2 pipelined 8-phase, grid 32x16 = 512
    gemm8p<true, true, bf16><<<dim3(512), dim3(512), 0, stream>>>(
        xn2, 1024, w1t, 1024, b1, hb, 4096, M, 4096, 1024);

    gemm_bt<64, false, true, true, bf16, float><<<dim3(8, 64), blk, 0, stream>>>(
        hb, 4096, w2t, 4096, b2, x1b, 1024, (float*)d_out, 1024, M, 1024, 4096);
}

// Round 9
// 482.690 us; speedup vs baseline: 1.0441x; 1.0441x over previous
//
#include <hip/hip_runtime.h>
#include <hip/hip_bf16.h>

typedef __hip_bfloat16 bf16;
typedef __attribute__((ext_vector_type(8))) short bf16x8;
typedef __attribute__((ext_vector_type(4))) short s16x4;
typedef __attribute__((ext_vector_type(4))) float f32x4;
typedef __attribute__((ext_vector_type(2))) unsigned int u32x2;

__device__ __forceinline__ float b2f(bf16 v) { return __bfloat162float(v); }
__device__ __forceinline__ bf16  f2b(float v) { return __float2bfloat16(v); }
__device__ __forceinline__ float ldf(const bf16* p)  { return __bfloat162float(*p); }
__device__ __forceinline__ float ldf(const float* p) { return *p; }
__device__ __forceinline__ void  stf(bf16* p, float v)  { *p = __float2bfloat16(v); }
__device__ __forceinline__ void  stf(float* p, float v) { *p = v; }

// HW packed f32x2 -> bf16x2 convert (RNE). No builtin on gfx950 (T12 recipe).
__device__ __forceinline__ unsigned cvt_pk_bf16(float lo, float hi) {
    unsigned r;
    asm("v_cvt_pk_bf16_f32 %0, %1, %2" : "=v"(r) : "v"(lo), "v"(hi));
    return r;
}

// vectorized 4-element row loads for LayerNorm
__device__ __forceinline__ void ld4(const float* p, float* v) {
    float4 t = *(const float4*)p;
    v[0] = t.x; v[1] = t.y; v[2] = t.z; v[3] = t.w;
}
__device__ __forceinline__ void ld4(const bf16* p, float* v) {
    s16x4 t = *(const s16x4*)p;
#pragma unroll
    for (int j = 0; j < 4; ++j) { short s = t[j]; v[j] = b2f(*(bf16*)&s); }
}

// async global->LDS, 16 B per lane; LDS dest = wave-uniform base + lane*16
__device__ __forceinline__ void load_lds16(const bf16* g, short* lds) {
    __builtin_amdgcn_global_load_lds(
        (const __attribute__((address_space(1))) unsigned int*)g,
        (__attribute__((address_space(3))) unsigned int*)lds, 16, 0, 0);
}

// ---------------------------------------------------------------------------
// LayerNorm over last dim C=1024. One block (256 threads) per row. bf16 out.
// ---------------------------------------------------------------------------
template<typename InT>
__global__ __launch_bounds__(256) void ln_kernel(const InT* __restrict__ x,
                                                 const float* __restrict__ g,
                                                 const float* __restrict__ b,
                                                 bf16* __restrict__ out)
{
    const int C = 1024;
    int row = blockIdx.x;
    int tid = threadIdx.x;
    const InT* xr = x + (size_t)row * C;

    float v[4];
    ld4(xr + tid * 4, v);
    float s = 0.f, s2 = 0.f;
#pragma unroll
    for (int i = 0; i < 4; ++i) { s += v[i]; s2 += v[i] * v[i]; }
#pragma unroll
    for (int off = 32; off > 0; off >>= 1) {
        s  += __shfl_down(s,  off, 64);
        s2 += __shfl_down(s2, off, 64);
    }
    __shared__ float red[8];
    int wave = tid >> 6;
    if ((tid & 63) == 0) { red[wave] = s; red[wave + 4] = s2; }
    __syncthreads();
    float ts  = red[0] + red[1] + red[2] + red[3];
    float ts2 = red[4] + red[5] + red[6] + red[7];
    float mu  = ts * (1.f / 1024.f);
    float var = ts2 * (1.f / 1024.f) - mu * mu;
    float rstd = rsqrtf(var + 1e-5f);

    float4 gg = *(const float4*)(g + tid * 4);
    float4 bb = *(const float4*)(b + tid * 4);
    float gj[4] = {gg.x, gg.y, gg.z, gg.w};
    float bj[4] = {bb.x, bb.y, bb.z, bb.w};
    s16x4 o4;
#pragma unroll
    for (int j = 0; j < 4; ++j) {
        bf16 ob = f2b((v[j] - mu) * rstd * gj[j] + bj[j]);
        o4[j] = *(short*)&ob;
    }
    *(s16x4*)(out + (size_t)row * C + tid * 4) = o4;
}

// ---------------------------------------------------------------------------
// All six weight transposes (fp32 -> bf16, out[n][k] = in[k][n]) in ONE
// kernel. Flat tile id selects matrix + 32x32 tile.
// ---------------------------------------------------------------------------
__global__ __launch_bounds__(256) void prep_weights(
    const float* __restrict__ Wq, const float* __restrict__ Wk,
    const float* __restrict__ Wv, const float* __restrict__ Wo,
    const float* __restrict__ W1, const float* __restrict__ W2,
    bf16* __restrict__ wqkvt, bf16* __restrict__ wot,
    bf16* __restrict__ w1t, bf16* __restrict__ w2t)
{
    __shared__ float t[32][33];
    int tx = threadIdx.x & 31, ty = threadIdx.x >> 5;
    int id = blockIdx.x;
    const float* in; bf16* out; int in_ld, out_ld, n0, k0;
    if (id < 3072) {
        const float* Ws[3] = {Wq, Wk, Wv};
        int m = id >> 10, r = id & 1023;
        int z = r >> 6, rt = r & 63;
        in = Ws[m] + z * 65536;                       // [1024][64]
        out = wqkvt + (size_t)(m * 1024 + z * 64) * 1024;
        in_ld = 64; out_ld = 1024;
        n0 = (rt & 1) * 32; k0 = (rt >> 1) * 32;
    } else if (id < 4096) {
        int r = id - 3072;
        in = Wo; out = wot; in_ld = 1024; out_ld = 1024;
        n0 = (r & 31) * 32; k0 = (r >> 5) * 32;
    } else if (id < 8192) {
        int r = id - 4096;
        in = W1; out = w1t; in_ld = 4096; out_ld = 1024;
        n0 = (r & 127) * 32; k0 = (r >> 7) * 32;
    } else {
        int r = id - 8192;
        in = W2; out = w2t; in_ld = 1024; out_ld = 4096;
        n0 = (r & 31) * 32; k0 = (r >> 5) * 32;
    }
#pragma unroll
    for (int i = 0; i < 4; ++i)
        t[ty + i * 8][tx] = in[(size_t)(k0 + ty + i * 8) * in_ld + n0 + tx];
    __syncthreads();
#pragma unroll
    for (int i = 0; i < 4; ++i)
        out[(size_t)(n0 + ty + i * 8) * out_ld + k0 + tx] = f2b(t[tx][ty + i * 8]);
}

// ---------------------------------------------------------------------------
// V^T: vt[(b*16+h)*64 + d][t] = qkv[(b*T+t)*3072 + 2048 + h*64 + d]
// ---------------------------------------------------------------------------
__global__ __launch_bounds__(256) void vt_kernel(
    const bf16* __restrict__ qkv, bf16* __restrict__ vt, int T)
{
    __shared__ float t[32][33];
    int tx = threadIdx.x & 31, ty = threadIdx.x >> 5;
    int z = blockIdx.z, b = z >> 4, h = z & 15;
    const bf16* in = qkv + (size_t)b * T * 3072 + 2048 + h * 64;  // [t][d] ld 3072
    bf16* out = vt + (size_t)z * 64 * T;                          // [d][t] ld T
    int n0 = blockIdx.x * 32, k0 = blockIdx.y * 32;
#pragma unroll
    for (int i = 0; i < 4; ++i)
        t[ty + i * 8][tx] = b2f(in[(size_t)(k0 + ty + i * 8) * 3072 + n0 + tx]);
    __syncthreads();
#pragma unroll
    for (int i = 0; i < 4; ++i)
        out[(size_t)(n0 + ty + i * 8) * T + k0 + tx] = f2b(t[tx][ty + i * 8]);
}

// ---------------------------------------------------------------------------
// 256x256 MFMA GEMM (T2+T3+T4+T5), plain HIP. 512 thr = 8 waves.
// REVERTED to the R6-verified body (82.8 us FFN1, MfmaUtil 33.5) -- the R8
// pipelined-fragment-read experiment regressed (96 us, in-order DS returns
// put 8 newer reads ahead of the needed frags on the lgkmcnt chain; +12 VGPR).
// BK=32, FOUR LDS buffers (128 KB), staging 3 tiles ahead alias-free.
// 2 phases/K-tile, ds_reads balanced 8/4; counted vmcnt never 0 in steady
// state; verified 0-conflict swizzle.
// Requires: M%256==0, N%256==0, K%32==0, K/32>=4, grid %8==0.
// ---------------------------------------------------------------------------
template<bool RELU, bool HAS_BIAS, typename OutT>
__global__ __launch_bounds__(512, 2) void gemm8p(
    const bf16* __restrict__ A, int lda,
    const bf16* __restrict__ Bt, int ldb,
    const float* __restrict__ bias,
    OutT* __restrict__ Cm, int ldc,
    int M, int N, int K)
{
    __shared__ short As[4][8192];
    __shared__ short Bs[4][8192];
    int tid = threadIdx.x, wv = tid >> 6, ln = tid & 63;
    int quad = ln >> 4, lane15 = ln & 15;

    // XCD-chunked bijective remap (nwg % 8 == 0)
    int nbn = N >> 8;
    int nwg = gridDim.x;
    int f2 = (blockIdx.x & 7) * (nwg >> 3) + (blockIdx.x >> 3);
    int by = f2 / nbn, bx = f2 % nbn;
    int bm0 = by << 8, bn0 = bx << 8;

    int wr = wv >> 2, wc = wv & 3;     // wave row-half / col-quarter
    const int NT = K >> 5;

    // staging addresses (per thread); linear LDS dest, swizzled source
    int sr = tid >> 2;                                  // row 0..127
    int sc = ((tid & 3) ^ ((sr >> 1) & 3)) * 8;
    const bf16* Ab1 = A  + (size_t)(bm0 + sr) * lda + sc;
    const bf16* Ab2 = A  + (size_t)(bm0 + 128 + sr) * lda + sc;
    const bf16* Bb1 = Bt + (size_t)(bn0 + sr) * ldb + sc;
    const bf16* Bb2 = Bt + (size_t)(bn0 + 128 + sr) * ldb + sc;

#define STAGE_A8(bf_, u_) { \
    load_lds16(Ab1 + (u_) * 32, &As[bf_][wv * 512]); \
    load_lds16(Ab2 + (u_) * 32, &As[bf_][4096 + wv * 512]); }
#define STAGE_B8(bf_, u_) { \
    load_lds16(Bb1 + (u_) * 32, &Bs[bf_][wv * 512]); \
    load_lds16(Bb2 + (u_) * 32, &Bs[bf_][4096 + wv * 512]); }

    f32x4 acc[8][4] = {};                 // 128 VGPRs
    int arow = wr * 128 + lane15;
    int brow = wc * 64 + lane15;
    int sw = (quad ^ ((lane15 >> 1) & 3)) * 8;

    // prologue: stage tiles 0,1,2; wait tile 0 (8 loads stay in flight)
    STAGE_A8(0, 0); STAGE_B8(0, 0);
    STAGE_A8(1, 1); STAGE_B8(1, 1);
    STAGE_A8(2, 2); STAGE_B8(2, 2);
    asm volatile("s_waitcnt vmcnt(8)" ::: "memory");
    __builtin_amdgcn_s_barrier();

    for (int t = 0; t < NT; ++t) {
        int buf = t & 3;
        const short* Al = &As[buf][0];
        const short* Bl = &Bs[buf][0];

        // ---- phase 0: af[0..3] + bf[0..3]; stage A(t+3)
        bf16x8 af[4], bfr[4];
#pragma unroll
        for (int mi = 0; mi < 4; ++mi)
            af[mi] = *(const bf16x8*)&Al[(arow + mi * 16) * 32 + sw];
#pragma unroll
        for (int ni = 0; ni < 4; ++ni)
            bfr[ni] = *(const bf16x8*)&Bl[(brow + ni * 16) * 32 + sw];
        if (t + 3 < NT) STAGE_A8((t + 3) & 3, t + 3);
        __builtin_amdgcn_s_barrier();
        __builtin_amdgcn_s_setprio(1);
#pragma unroll
        for (int mi = 0; mi < 4; ++mi)
#pragma unroll
            for (int ni = 0; ni < 4; ++ni)
                acc[mi][ni] = __builtin_amdgcn_mfma_f32_16x16x32_bf16(
                    af[mi], bfr[ni], acc[mi][ni], 0, 0, 0);
        __builtin_amdgcn_s_setprio(0);
        __builtin_amdgcn_s_barrier();

        // ---- phase 1: af[4..7] (bf in regs); stage B(t+3); counted wait
        bf16x8 ag[4];
#pragma unroll
        for (int mi = 0; mi < 4; ++mi)
            ag[mi] = *(const bf16x8*)&Al[(arow + (mi + 4) * 16) * 32 + sw];
        if (t + 3 < NT) STAGE_B8((t + 3) & 3, t + 3);
        if (t < NT - 3) {
            asm volatile("s_waitcnt vmcnt(8)" ::: "memory");   // tile t+1 landed
        } else if (t == NT - 3) {
            asm volatile("s_waitcnt vmcnt(4)" ::: "memory");
        } else if (t == NT - 2) {
            asm volatile("s_waitcnt vmcnt(0)" ::: "memory");   // tail only
        }
        __builtin_amdgcn_s_barrier();
        __builtin_amdgcn_s_setprio(1);
#pragma unroll
        for (int mi = 0; mi < 4; ++mi)
#pragma unroll
            for (int ni = 0; ni < 4; ++ni)
                acc[mi + 4][ni] = __builtin_amdgcn_mfma_f32_16x16x32_bf16(
                    ag[mi], bfr[ni], acc[mi + 4][ni], 0, 0, 0);
        __builtin_amdgcn_s_setprio(0);
        __builtin_amdgcn_s_barrier();
    }

#undef STAGE_A8
#undef STAGE_B8

    // ---- epilogue
#pragma unroll
    for (int mi = 0; mi < 8; ++mi) {
#pragma unroll
        for (int r = 0; r < 4; ++r) {
            int gm = bm0 + wr * 128 + mi * 16 + quad * 4 + r;
#pragma unroll
            for (int ni = 0; ni < 4; ++ni) {
                int gn = bn0 + wc * 64 + ni * 16 + lane15;
                float v = acc[mi][ni][r];
                if (HAS_BIAS) v += bias[gn];
                if (RELU)     v = fmaxf(v, 0.f);
                stf(Cm + (size_t)gm * ldc + gn, v);
            }
        }
    }
}

// ---------------------------------------------------------------------------
// MFMA GEMM: C[M,N] = A[M,K] @ B[K,N], B given TRANSPOSED (Bt[n][k]).
// 128x128 tile, 256 thr = 4 waves, templated BK (32 or 64). Double-buffered
// LDS, stage-before-compute, one __syncthreads per K-step. Used for the
// N=1024 GEMMs (Wo, FFN2) where 256-wide col tiles would underfill the grid.
// ---------------------------------------------------------------------------
template<int BK, bool RELU, bool HAS_BIAS, bool HAS_RES, typename ResT, typename OutT>
__global__ __launch_bounds__(256) void gemm_bt(
    const bf16* __restrict__ A, int lda,
    const bf16* __restrict__ Bt, int ldb,
    const float* __restrict__ bias,
    const ResT* __restrict__ res, int ldr,
    OutT* __restrict__ Cm, int ldc,
    int M, int N, int K)
{
    __shared__ short As[2][128 * BK];
    __shared__ short Bs[2][128 * BK];
    int tid = threadIdx.x, wv = tid >> 6, ln = tid & 63;

    int f = blockIdx.x + blockIdx.y * gridDim.x;
    int nby = gridDim.y;
    int by = f % nby, bx = f / nby;
    int bm0 = by * 128, bn0 = bx * 128;

    int wm = (wv & 1) * 64, wn = (wv >> 1) * 64;
    int quad = ln >> 4, lane15 = ln & 15;

    f32x4 acc[4][4] = {};

    const bf16* Ab = A + (size_t)bm0 * lda;
    const bf16* Bb = Bt + (size_t)bn0 * ldb;

    auto stage = [&](int buf, int kk) {
        if constexpr (BK == 32) {
            int srow = ln >> 2;
            int scol = (((ln & 3) ^ ((ln >> 3) & 3)) * 8);
#pragma unroll
            for (int i = 0; i < 2; ++i) {
                int ch = wv + i * 4;
                load_lds16(Ab + (size_t)(ch * 16 + srow) * lda + kk + scol,
                           &As[buf][ch * 16 * 32]);
                load_lds16(Bb + (size_t)(ch * 16 + srow) * ldb + kk + scol,
                           &Bs[buf][ch * 16 * 32]);
            }
        } else {
            int srow = ln >> 3;
            int scol = ((ln & 7) ^ srow) * 8;
#pragma unroll
            for (int i = 0; i < 4; ++i) {
                int r0 = i * 32 + wv * 8;
                load_lds16(Ab + (size_t)(r0 + srow) * lda + kk + scol,
                           &As[buf][r0 * 64]);
                load_lds16(Bb + (size_t)(r0 + srow) * ldb + kk + scol,
                           &Bs[buf][r0 * 64]);
            }
        }
    };

    stage(0, 0);
    __syncthreads();

    int cur = 0;
    for (int k0 = 0; k0 < K; k0 += BK) {
        if (k0 + BK < K) stage(cur ^ 1, k0 + BK);
        if constexpr (BK == 32) {
            int sw = (quad ^ ((lane15 >> 1) & 3)) * 8;
            bf16x8 af[4], bfr[4];
#pragma unroll
            for (int mi = 0; mi < 4; ++mi)
                af[mi] = *(const bf16x8*)&As[cur][(wm + mi * 16 + lane15) * 32 + sw];
#pragma unroll
            for (int ni = 0; ni < 4; ++ni)
                bfr[ni] = *(const bf16x8*)&Bs[cur][(wn + ni * 16 + lane15) * 32 + sw];
#pragma unroll
            for (int mi = 0; mi < 4; ++mi)
#pragma unroll
                for (int ni = 0; ni < 4; ++ni)
                    acc[mi][ni] = __builtin_amdgcn_mfma_f32_16x16x32_bf16(
                        af[mi], bfr[ni], acc[mi][ni], 0, 0, 0);
        } else {
#pragma unroll
            for (int ks = 0; ks < 2; ++ks) {
                int sw = (((ks * 4 + quad) ^ (lane15 & 7)) * 8);
                bf16x8 af[4], bfr[4];
#pragma unroll
                for (int mi = 0; mi < 4; ++mi)
                    af[mi] = *(const bf16x8*)&As[cur][(wm + mi * 16 + lane15) * 64 + sw];
#pragma unroll
                for (int ni = 0; ni < 4; ++ni)
                    bfr[ni] = *(const bf16x8*)&Bs[cur][(wn + ni * 16 + lane15) * 64 + sw];
#pragma unroll
                for (int mi = 0; mi < 4; ++mi)
#pragma unroll
                    for (int ni = 0; ni < 4; ++ni)
                        acc[mi][ni] = __builtin_amdgcn_mfma_f32_16x16x32_bf16(
                            af[mi], bfr[ni], acc[mi][ni], 0, 0, 0);
            }
        }
        __syncthreads();
        cur ^= 1;
    }

#pragma unroll
    for (int mi = 0; mi < 4; ++mi) {
#pragma unroll
        for (int r = 0; r < 4; ++r) {
            int gm = bm0 + wm + mi * 16 + quad * 4 + r;
#pragma unroll
            for (int ni = 0; ni < 4; ++ni) {
                int gn = bn0 + wn + ni * 16 + lane15;
                float v = acc[mi][ni][r];
                if (HAS_BIAS) v += bias[gn];
                if (HAS_RES)  v += ldf(res + (size_t)gm * ldr + gn);
                if (RELU)     v = fmaxf(v, 0.f);
                stf(Cm + (size_t)gm * ldc + gn, v);
            }
        }
    }
}

// ---------------------------------------------------------------------------
// Single q-tile per 64-key tile (used when only the heavy tile is active):
// QK^T (S^T form), constant-shift softmax in exp2 domain, P->LDS, PV.
// ---------------------------------------------------------------------------
__device__ __forceinline__ void attn_tile_q(
    const short* __restrict__ Ks, const short* __restrict__ Vs,
    short* __restrict__ Psw,
    const bf16x8* qf, f32x4* oacc, float& lrun,
    int ktbase, int qmin, int quad, int lane15, int r7)
{
    const float scale2 = 0.18033688011112042f;   // (1/8) * log2(e)
    const int PS = 72;
    f32x4 sacc[4] = {};
    __builtin_amdgcn_s_setprio(1);
#pragma unroll
    for (int ks = 0; ks < 2; ++ks) {
        int so = ((ks * 4 + quad) ^ r7) * 8;
#pragma unroll
        for (int mi = 0; mi < 4; ++mi) {
            bf16x8 kf = *(const bf16x8*)&Ks[(mi * 16 + lane15) * 64 + so];
            sacc[mi] = __builtin_amdgcn_mfma_f32_16x16x32_bf16(kf, qf[ks], sacc[mi], 0, 0, 0);
        }
    }
    __builtin_amdgcn_s_setprio(0);

    if (ktbase + 63 > qmin) {
        int ql = qmin + lane15;
#pragma unroll
        for (int mi = 0; mi < 4; ++mi)
#pragma unroll
            for (int r = 0; r < 4; ++r)
                if (ktbase + mi * 16 + quad * 4 + r > ql) sacc[mi][r] = -3e38f;
    }

    float psum = 0.f;
#pragma unroll
    for (int mi = 0; mi < 4; ++mi) {
        float p[4];
#pragma unroll
        for (int r = 0; r < 4; ++r) {
            p[r] = exp2f(sacc[mi][r] * scale2);
            psum += p[r];
        }
        u32x2 pu;
        pu[0] = cvt_pk_bf16(p[0], p[1]);
        pu[1] = cvt_pk_bf16(p[2], p[3]);
        *(u32x2*)&Psw[lane15 * PS + mi * 16 + quad * 4] = pu;
    }
    lrun += psum;

    __builtin_amdgcn_s_setprio(1);
#pragma unroll
    for (int ks = 0; ks < 2; ++ks) {
        int so = ((ks * 4 + quad) ^ r7) * 8;
        bf16x8 pf = *(const bf16x8*)&Psw[lane15 * PS + ks * 32 + quad * 8];
#pragma unroll
        for (int di = 0; di < 4; ++di) {
            bf16x8 vf = *(const bf16x8*)&Vs[(di * 16 + lane15) * 64 + so];
            oacc[di] = __builtin_amdgcn_mfma_f32_16x16x32_bf16(vf, pf, oacc[di], 0, 0, 0);
        }
    }
    __builtin_amdgcn_s_setprio(0);
}

// ---------------------------------------------------------------------------
// FUSED dual q-tile per 64-key tile: each kf/vf LDS read feeds TWO MFMAs
// (tile a and tile b) -- halves K/V LDS-read traffic on dual-active
// iterations (the attn limiter: ~216 LDS-read cyc vs 78 MFMA cyc per wave
// per tile-unit). On dual-active iterations tile a is never mask-crossed
// (kb <= qminb+127 < qta*128 <= qmina for all bx), so only b is masked.
// ---------------------------------------------------------------------------
__device__ __forceinline__ void attn_tile_q_dual(
    const short* __restrict__ Ks, const short* __restrict__ Vs,
    short* __restrict__ Psa, short* __restrict__ Psb,
    const bf16x8* qfa, const bf16x8* qfb,
    f32x4* oacca, f32x4* oaccb, float& lra, float& lrb,
    int ktbase, int qminb, int quad, int lane15, int r7)
{
    const float scale2 = 0.18033688011112042f;   // (1/8) * log2(e)
    const int PS = 72;
    f32x4 sa[4] = {}, sb[4] = {};
    __builtin_amdgcn_s_setprio(1);
#pragma unroll
    for (int ks = 0; ks < 2; ++ks) {
        int so = ((ks * 4 + quad) ^ r7) * 8;
#pragma unroll
        for (int mi = 0; mi < 4; ++mi) {
            bf16x8 kf = *(const bf16x8*)&Ks[(mi * 16 + lane15) * 64 + so];
            sa[mi] = __builtin_amdgcn_mfma_f32_16x16x32_bf16(kf, qfa[ks], sa[mi], 0, 0, 0);
            sb[mi] = __builtin_amdgcn_mfma_f32_16x16x32_bf16(kf, qfb[ks], sb[mi], 0, 0, 0);
        }
    }
    __builtin_amdgcn_s_setprio(0);

    // mask only b (a provably unmasked on dual-active tiles)
    if (ktbase + 63 > qminb) {
        int ql = qminb + lane15;
#pragma unroll
        for (int mi = 0; mi < 4; ++mi)
#pragma unroll
            for (int r = 0; r < 4; ++r)
                if (ktbase + mi * 16 + quad * 4 + r > ql) sb[mi][r] = -3e38f;
    }

    float psa = 0.f, psb = 0.f;
#pragma unroll
    for (int mi = 0; mi < 4; ++mi) {
        float pa[4], pb[4];
#pragma unroll
        for (int r = 0; r < 4; ++r) {
            pa[r] = exp2f(sa[mi][r] * scale2);
            pb[r] = exp2f(sb[mi][r] * scale2);
            psa += pa[r]; psb += pb[r];
        }
        u32x2 ua, ub;
        ua[0] = cvt_pk_bf16(pa[0], pa[1]);
        ua[1] = cvt_pk_bf16(pa[2], pa[3]);
        ub[0] = cvt_pk_bf16(pb[0], pb[1]);
        ub[1] = cvt_pk_bf16(pb[2], pb[3]);
        *(u32x2*)&Psa[lane15 * PS + mi * 16 + quad * 4] = ua;
        *(u32x2*)&Psb[lane15 * PS + mi * 16 + quad * 4] = ub;
    }
    lra += psa; lrb += psb;

    __builtin_amdgcn_s_setprio(1);
#pragma unroll
    for (int ks = 0; ks < 2; ++ks) {
        int so = ((ks * 4 + quad) ^ r7) * 8;
        bf16x8 pfa = *(const bf16x8*)&Psa[lane15 * PS + ks * 32 + quad * 8];
        bf16x8 pfb = *(const bf16x8*)&Psb[lane15 * PS + ks * 32 + quad * 8];
#pragma unroll
        for (int di = 0; di < 4; ++di) {
            bf16x8 vf = *(const bf16x8*)&Vs[(di * 16 + lane15) * 64 + so];
            oacca[di] = __builtin_amdgcn_mfma_f32_16x16x32_bf16(vf, pfa, oacca[di], 0, 0, 0);
            oaccb[di] = __builtin_amdgcn_mfma_f32_16x16x32_bf16(vf, pfb, oaccb[di], 0, 0, 0);
        }
    }
    __builtin_amdgcn_s_setprio(0);
}

// ---------------------------------------------------------------------------
// MFMA causal flash attention, S^T form, 512 thr = 8 waves.
// CAUSAL-BALANCED DUAL Q-TILE: block bx processes q-tiles (15-bx, bx) in ONE
// k-loop sharing K/V staging AND (this round) sharing K/V fragment reads via
// the fused dual-tile path. Constant-shift softmax (no running max).
// ---------------------------------------------------------------------------
__global__ __launch_bounds__(512, 4) void attn_kernel(
    const bf16* __restrict__ qkv, const bf16* __restrict__ vt,
    bf16* __restrict__ o, int T)
{
    const int LDQ = 3072;
    const int PS = 72;
    int bx = blockIdx.x;
    int qta = 15 - bx;
    int qtb = bx;
    int h = blockIdx.y, b = blockIdx.z;
    int tid = threadIdx.x, wv = tid >> 6, ln = tid & 63;
    int quad = ln >> 4, lane15 = ln & 15, r7 = lane15 & 7;

    __shared__ short KV[2][2][64 * 64];
    __shared__ short Ps[2][8][16 * PS];

    int lr = ln >> 3;
    int lc = ((ln & 7) ^ lr) * 8;

    const bf16* kbase = qkv + (size_t)(b * T) * LDQ + 1024 + h * 64;
    const bf16* vbase = vt + (size_t)((b * 16 + h) * 64) * T;

#pragma unroll
    for (int i = 0; i < 2; ++i) {
        int ch = wv * 2 + i;
        load_lds16(qkv + (size_t)(b * T + qta * 128 + ch * 8 + lr) * LDQ + h * 64 + lc,
                   &KV[0][0][ch * 512]);
        load_lds16(qkv + (size_t)(b * T + qtb * 128 + ch * 8 + lr) * LDQ + h * 64 + lc,
                   &KV[1][0][ch * 512]);
    }
    __syncthreads();
    bf16x8 qfa[2], qfb[2];
#pragma unroll
    for (int ks = 0; ks < 2; ++ks) {
        int off = (wv * 16 + lane15) * 64 + (((ks * 4 + quad) ^ r7) * 8);
        qfa[ks] = *(const bf16x8*)&KV[0][0][off];
        qfb[ks] = *(const bf16x8*)&KV[1][0][off];
    }
    __syncthreads();

    f32x4 oacca[4] = {}, oaccb[4] = {};
    float lra = 0.f, lrb = 0.f;
    int qmina = qta * 128 + wv * 16;
    int qminb = qtb * 128 + wv * 16;
    int ntiles = 2 * qta + 2;

    // per-thread incremental staging pointers (tile 0)
    const bf16* kp = kbase + (size_t)(wv * 8 + lr) * LDQ + lc;
    const bf16* vp = vbase + (size_t)(wv * 8 + lr) * T + lc;
    load_lds16(kp, &KV[0][0][wv * 8 * 64]);
    load_lds16(vp, &KV[0][1][wv * 8 * 64]);

    for (int kt = 0; kt < ntiles; ++kt) {
        __syncthreads();
        if (kt + 1 < ntiles) {
            int nb = (kt + 1) & 1;
            kp += 64 * LDQ;     // next key tile: +64 rows
            vp += 64;           // next key tile: +64 cols
            load_lds16(kp, &KV[nb][0][wv * 8 * 64]);
            load_lds16(vp, &KV[nb][1][wv * 8 * 64]);
        }
        const short* Ks = &KV[kt & 1][0][0];
        const short* Vs = &KV[kt & 1][1][0];
        int kb = kt * 64;

        if (kb <= qminb + 15) {
            // both tiles active: fused path, shared kf/vf reads
            attn_tile_q_dual(Ks, Vs, &Ps[0][wv][0], &Ps[1][wv][0],
                             qfa, qfb, oacca, oaccb, lra, lrb,
                             kb, qminb, quad, lane15, r7);
        } else if (kb <= qmina + 15) {
            attn_tile_q(Ks, Vs, &Ps[0][wv][0], qfa, oacca, lra,
                        kb, qmina, quad, lane15, r7);
        }
    }

    lra += __shfl_xor(lra, 16, 64);
    lra += __shfl_xor(lra, 32, 64);
    float inva = 1.f / lra;
    size_t rowa = (size_t)(b * T + qta * 128 + wv * 16 + lane15);
#pragma unroll
    for (int di = 0; di < 4; ++di) {
        u32x2 ou;
        ou[0] = cvt_pk_bf16(oacca[di][0] * inva, oacca[di][1] * inva);
        ou[1] = cvt_pk_bf16(oacca[di][2] * inva, oacca[di][3] * inva);
        *(u32x2*)&o[rowa * 1024 + h * 64 + di * 16 + quad * 4] = ou;
    }

    lrb += __shfl_xor(lrb, 16, 64);
    lrb += __shfl_xor(lrb, 32, 64);
    float invb = 1.f / lrb;
    size_t rowb = (size_t)(b * T + qtb * 128 + wv * 16 + lane15);
#pragma unroll
    for (int di = 0; di < 4; ++di) {
        u32x2 ou;
        ou[0] = cvt_pk_bf16(oaccb[di][0] * invb, oaccb[di][1] * invb);
        ou[1] = cvt_pk_bf16(oaccb[di][2] * invb, oaccb[di][3] * invb);
        *(u32x2*)&o[rowb * 1024 + h * 64 + di * 16 + quad * 4] = ou;
    }
}

// ---------------------------------------------------------------------------
extern "C" void kernel_launch(void* const* d_in, const int* in_sizes, int n_in,
                              void* d_out, int out_size, void* d_ws, size_t ws_size,
                              hipStream_t stream)
{
    (void)in_sizes; (void)n_in; (void)out_size; (void)ws_size;
    const float* x   = (const float*)d_in[0];
    const float* Wq  = (const float*)d_in[1];
    const float* Wk  = (const float*)d_in[2];
    const float* Wv  = (const float*)d_in[3];
    const float* Wo  = (const float*)d_in[4];
    const float* bo  = (const float*)d_in[5];
    const float* g1  = (const float*)d_in[6];
    const float* be1 = (const float*)d_in[7];
    const float* g2  = (const float*)d_in[8];
    const float* be2 = (const float*)d_in[9];
    const float* W1  = (const float*)d_in[10];
    const float* b1  = (const float*)d_in[11];
    const float* W2  = (const float*)d_in[12];
    const float* b2  = (const float*)d_in[13];

    const int T = 2048, M = 4 * T;  // 8192 rows
    const size_t MB = 1ull << 20;
    char* ws = (char*)d_ws;

    // workspace map (128 MB, live-range overlays):
    bf16*  xn    = (bf16*)(ws + 0 * MB);     // 16 MB; later: attnb; later: hb
    bf16*  qkv   = (bf16*)(ws + 16 * MB);    // 48 MB [M][3072]; later: hb tail
    bf16*  vt    = (bf16*)(ws + 64 * MB);    // 16 MB [b*16+h][64][T]
    bf16*  wqkvt = (bf16*)(ws + 80 * MB);    //  6 MB [3072][1024]; later: x1b
    bf16*  x1b   = (bf16*)(ws + 80 * MB);    // 16 MB [M][1024] bf16 residual
    bf16*  wot   = (bf16*)(ws + 96 * MB);    //  2 MB; later: xn2
    bf16*  xn2   = (bf16*)(ws + 96 * MB);    // 16 MB
    bf16*  w1t   = (bf16*)(ws + 112 * MB);   //  8 MB [4096][1024]
    bf16*  w2t   = (bf16*)(ws + 120 * MB);   //  8 MB [1024][4096]
    bf16*  attnb = (bf16*)(ws + 0 * MB);
    bf16*  hb    = (bf16*)(ws + 0 * MB);     // 64 MB [M][4096]

    dim3 blk(256);

    prep_weights<<<12288, blk, 0, stream>>>(Wq, Wk, Wv, Wo, W1, W2,
                                            wqkvt, wot, w1t, w2t);

    ln_kernel<float><<<M, blk, 0, stream>>>(x, g1, be1, xn);

    // QKV: 256^2 8-phase, grid 32x12 = 384
    gemm8p<false, false, bf16><<<dim3(384), dim3(512), 0, stream>>>(
        xn, 1024, wqkvt, 1024, nullptr, qkv, 3072, M, 3072, 1024);

    vt_kernel<<<dim3(2, T / 32, 64), blk, 0, stream>>>(qkv, vt, T);

    attn_kernel<<<dim3(8, 16, 4), dim3(512), 0, stream>>>(qkv, vt, attnb, T);

    gemm_bt<32, false, true, true, float, bf16><<<dim3(8, 64), blk, 0, stream>>>(
        attnb, 1024, wot, 1024, bo, x, 1024, x1b, 1024, M, 1024, 1024);

    ln_kernel<bf16><<<M, blk, 0, stream>>>(x1b, g2, be2, xn2);

    // FFN1: 256^2 8-phase, grid 32x16 = 512
    gemm8p<true, true, bf16><<<dim3(512), dim3(512), 0, stream>>>(
        xn2, 1024, w1t, 1024, b1, hb, 4096, M, 4096, 1024);

    gemm_bt<64, false, true, true, bf16, float><<<dim3(8, 64), blk, 0, stream>>>(
        hb, 4096, w2t, 4096, b2, x1b, 1024, (float*)d_out, 1024, M, 1024, 4096);
}